// Round 1
// baseline (889.134 us; speedup 1.0000x reference)
//
#include <hip/hip_runtime.h>
#include <math.h>

#define NB 512
#define SL 200
#define EK 64
#define NPROTO 16
#define PTD 256
#define XDIM 960

// ---------------- kernel 0: normalize prototypes -> pn_t[d*16+p] ----------------
__global__ __launch_bounds__(256) void k_protonorm(const float* __restrict__ protos,
                                                   float* __restrict__ pn_t) {
    __shared__ float part[256];
    __shared__ float rn[NPROTO];
    int t = threadIdx.x;
    int p = t >> 4, ch = t & 15;
    float s = 0.f;
    #pragma unroll
    for (int j = 0; j < 16; ++j) {
        float v = protos[p*PTD + ch*16 + j];
        s += v*v;
    }
    part[t] = s;
    __syncthreads();
    if (ch == 0) {
        float tot = 0.f;
        #pragma unroll
        for (int j = 0; j < 16; ++j) tot += part[p*16 + j];
        rn[p] = 1.0f / sqrtf(tot);
    }
    __syncthreads();
    #pragma unroll
    for (int i = 0; i < 16; ++i) {
        int e = i*256 + t;
        int pp = e & 15, d = e >> 4;
        pn_t[e] = protos[pp*PTD + d] * rn[pp];
    }
}

// ---------------- kernel 1: embeddings, pooling, x assembly, proto argmax ----------------
__global__ __launch_bounds__(512) void k_embed(
    const int* __restrict__ uf0, const int* __restrict__ uf1, const int* __restrict__ uf2,
    const int* __restrict__ if0, const int* __restrict__ if1, const int* __restrict__ if2, const int* __restrict__ if3,
    const int* __restrict__ sq0, const int* __restrict__ sq1, const int* __restrict__ sq2, const int* __restrict__ sq3,
    const float* __restrict__ ut0, const float* __restrict__ ut1, const float* __restrict__ ut2,
    const float* __restrict__ it0, const float* __restrict__ it1, const float* __restrict__ it2, const float* __restrict__ it3,
    const float* __restrict__ protos,
    float* __restrict__ x, int* __restrict__ kidx)
{
    int b = blockIdx.x;
    int t = threadIdx.x;
    int w = t >> 6, lane = t & 63;
    __shared__ float part[8][64];
    __shared__ float item_l[256];
    __shared__ float cnt_l[2];
    __shared__ float sim_l[NPROTO];

    int tbl = w & 3, half = w >> 2;
    const float* tab = (tbl==0) ? it0 : (tbl==1) ? it1 : (tbl==2) ? it2 : it3;
    const int*  seq  = (tbl==0) ? sq0 : (tbl==1) ? sq1 : (tbl==2) ? sq2 : sq3;
    const int* msk = sq0 + b*SL;
    const int* sqb = seq + b*SL;
    float acc = 0.f;
    int cnt = 0;
    int l0 = half * (SL/2);
    for (int l = l0; l < l0 + SL/2; ++l) {
        int mi = msk[l];
        if (mi != 0) {
            int idx = sqb[l];
            acc += tab[(size_t)idx*EK + lane];
            cnt++;
        }
    }
    part[w][lane] = acc;
    if (lane == 0 && tbl == 0) cnt_l[half] = (float)cnt;
    __syncthreads();
    if (w < 4) {
        const int* ifp = (w==0) ? if0 : (w==1) ? if1 : (w==2) ? if2 : if3;
        float iv = tab[(size_t)ifp[b]*EK + lane];
        float len = fmaxf(cnt_l[0] + cnt_l[1], 1.0f);
        float mean = (part[w][lane] + part[w+4][lane]) / len;
        item_l[w*64 + lane] = iv;
        size_t xb = (size_t)b * XDIM;
        x[xb + 192 + w*64 + lane] = iv;
        x[xb + 448 + w*64 + lane] = mean;
        x[xb + 704 + w*64 + lane] = iv * mean;
    } else if (w < 7) {
        int j = w - 4;
        const float* utab = (j==0) ? ut0 : (j==1) ? ut1 : ut2;
        const int* ufp  = (j==0) ? uf0 : (j==1) ? uf1 : uf2;
        float uv = utab[(size_t)ufp[b]*EK + lane];
        x[(size_t)b*XDIM + j*64 + lane] = uv;
    }
    __syncthreads();
    if (t < NPROTO) {
        // argmax of cosine sim; the positive 1/||item|| factor is argmax-invariant
        float dot = 0.f, n2 = 0.f;
        for (int d = 0; d < PTD; ++d) {
            float pv = protos[t*PTD + d];
            dot += pv * item_l[d];
            n2  += pv * pv;
        }
        sim_l[t] = dot / sqrtf(n2);
    }
    __syncthreads();
    if (t == 0) {
        float best = sim_l[0]; int bi = 0;
        for (int p = 1; p < NPROTO; ++p) if (sim_l[p] > best) { best = sim_l[p]; bi = p; }
        kidx[b] = bi;
    }
}

// ---------------- kernel: counting-sort samples by prototype ----------------
__global__ __launch_bounds__(512) void k_sort(const int* __restrict__ kidx, int* __restrict__ order) {
    __shared__ int cnt[NPROTO];
    __shared__ int base[NPROTO];
    int t = threadIdx.x;
    if (t < NPROTO) cnt[t] = 0;
    __syncthreads();
    int k = kidx[t];
    int myoff = atomicAdd(&cnt[k], 1);
    __syncthreads();
    if (t == 0) {
        int s = 0;
        for (int i = 0; i < NPROTO; ++i) { base[i] = s; s += cnt[i]; }
    }
    __syncthreads();
    order[base[k] + myoff] = t;
}

// ---------------- kernel 2: per-prototype hypernet weights ----------------
// out[k*C+c] = tanh( sum_d pn[k][d]*W[d*C+c] + bias[c] ) * scale[c]
__global__ __launch_bounds__(256) void k_hyper(
    const float* __restrict__ pn_t,
    const float* __restrict__ wtw0W, const float* __restrict__ wtw0b, const float* __restrict__ lin0W, float* __restrict__ Wg0,
    const float* __restrict__ wtw1W, const float* __restrict__ wtw1b, const float* __restrict__ lin1W, float* __restrict__ Wg1,
    const float* __restrict__ wtw2W, const float* __restrict__ wtw2b, const float* __restrict__ lin2W, float* __restrict__ Wg2,
    const float* __restrict__ wtb0W, const float* __restrict__ wtb0b, const float* __restrict__ lin0b, float* __restrict__ Bg0,
    const float* __restrict__ wtb1W, const float* __restrict__ wtb1b, const float* __restrict__ lin1b, float* __restrict__ Bg1,
    const float* __restrict__ wtb2W, const float* __restrict__ wtb2b, const float* __restrict__ lin2b, float* __restrict__ Bg2)
{
    __shared__ __align__(16) float pn_s[PTD*NPROTO];
    int t = threadIdx.x;
    for (int i = t; i < PTD*NPROTO; i += 256) pn_s[i] = pn_t[i];
    __syncthreads();

    int blk = blockIdx.x;
    const float* Wp; const float* bp; const float* sp; float* op; int C; int cbase;
    if (blk < 960)        { Wp=wtw0W; bp=wtw0b; sp=lin0W; op=Wg0; C=245760; cbase=blk*256; }
    else if (blk < 1088)  { Wp=wtw1W; bp=wtw1b; sp=lin1W; op=Wg1; C=32768;  cbase=(blk-960)*256; }
    else if (blk == 1088) { Wp=wtb0W; bp=wtb0b; sp=lin0b; op=Bg0; C=256;    cbase=0; }
    else if (blk == 1089) { Wp=wtb1W; bp=wtb1b; sp=lin1b; op=Bg1; C=128;    cbase=0; }
    else if (blk == 1090) { Wp=wtw2W; bp=wtw2b; sp=lin2W; op=Wg2; C=128;    cbase=0; }
    else                  { Wp=wtb2W; bp=wtb2b; sp=lin2b; op=Bg2; C=1;      cbase=0; }
    int c = cbase + t;
    if (c >= C) return;

    float acc[NPROTO];
    #pragma unroll
    for (int k = 0; k < NPROTO; ++k) acc[k] = 0.f;

    #pragma unroll 4
    for (int d = 0; d < PTD; ++d) {
        float wv = Wp[(size_t)d*C + c];
        #pragma unroll
        for (int k = 0; k < NPROTO; ++k) acc[k] += pn_s[d*NPROTO + k] * wv;
    }
    float bb = bp[c], ss = sp[c];
    #pragma unroll
    for (int k = 0; k < NPROTO; ++k) op[(size_t)k*C + c] = tanhf(acc[k] + bb) * ss;
}

// ---------------- kernel 3: per-sample MLP (origin + group chains) ----------------
__global__ __launch_bounds__(256) void k_mlp(
    const float* __restrict__ x, const int* __restrict__ kidx, const int* __restrict__ order,
    const float* __restrict__ lin0W, const float* __restrict__ lin0b,
    const float* __restrict__ lin1W, const float* __restrict__ lin1b,
    const float* __restrict__ lin2W, const float* __restrict__ lin2b,
    const float* __restrict__ Wg0, const float* __restrict__ Bg0,
    const float* __restrict__ Wg1, const float* __restrict__ Bg1,
    const float* __restrict__ Wg2, const float* __restrict__ Bg2,
    float* __restrict__ out)
{
    // XCD-aware: block i -> sorted position (i%8)*64 + i/8 so each XCD sees few prototypes
    int pos = ((blockIdx.x & 7) << 6) | (blockIdx.x >> 3);
    int b = order[pos];
    int t = threadIdx.x;
    int w = t >> 6, l = t & 63;
    __shared__ __align__(16) float xl[XDIM];
    __shared__ __align__(16) float o1[256], g1[256];
    __shared__ __align__(16) float o2[128], g2[128];
    __shared__ float red[256];
    for (int i = t; i < XDIM; i += 256) xl[i] = x[(size_t)b*XDIM + i];
    int k = kidx[b];
    __syncthreads();

    // ---- layer 0: 960 -> 256, both chains; lanes split the a-dim (coalesced W reads) ----
    {
        const float4* x4 = (const float4*)xl;
        float4 xv0 = x4[l];
        float4 xv1 = x4[l + 64];
        float4 xv2 = x4[l + 128];
        float4 xv3 = (l < 48) ? x4[l + 192] : make_float4(0.f, 0.f, 0.f, 0.f);
        int s3 = (l < 48) ? (l + 192) : 0;   // clamped; xv3==0 kills the bogus term
        const float4* wobase = (const float4*)lin0W;
        const float4* wgbase = (const float4*)(Wg0 + (size_t)k*245760);
        for (int hh = 0; hh < 64; ++hh) {
            int h = (w << 6) | hh;
            const float4* wo = wobase + h*240;
            const float4* wg = wgbase + h*240;
            float4 a, q;
            a = wo[l];       q = wg[l];
            float og = xv0.x*a.x + xv0.y*a.y + xv0.z*a.z + xv0.w*a.w;
            float gr = xv0.x*q.x + xv0.y*q.y + xv0.z*q.z + xv0.w*q.w;
            a = wo[l+64];    q = wg[l+64];
            og += xv1.x*a.x + xv1.y*a.y + xv1.z*a.z + xv1.w*a.w;
            gr += xv1.x*q.x + xv1.y*q.y + xv1.z*q.z + xv1.w*q.w;
            a = wo[l+128];   q = wg[l+128];
            og += xv2.x*a.x + xv2.y*a.y + xv2.z*a.z + xv2.w*a.w;
            gr += xv2.x*q.x + xv2.y*q.y + xv2.z*q.z + xv2.w*q.w;
            a = wo[s3];      q = wg[s3];
            og += xv3.x*a.x + xv3.y*a.y + xv3.z*a.z + xv3.w*a.w;
            gr += xv3.x*q.x + xv3.y*q.y + xv3.z*q.z + xv3.w*q.w;
            #pragma unroll
            for (int m = 32; m >= 1; m >>= 1) {
                og += __shfl_xor(og, m, 64);
                gr += __shfl_xor(gr, m, 64);
            }
            if (l == 0) {
                o1[h] = fmaxf(og + lin0b[h], 0.f);
                g1[h] = fmaxf(gr + Bg0[k*256 + h], 0.f);
            }
        }
    }
    __syncthreads();

    // ---- layer 1: 256 -> 128, waves 0-1 origin, waves 2-3 group ----
    {
        bool grp = (w >= 2);
        const float4* s4 = (const float4*)(grp ? g1 : o1);
        float4 sv = s4[l];
        int hbase = (w & 1) << 6;
        const float4* wb = grp ? (const float4*)(Wg1 + (size_t)k*32768)
                               : (const float4*)lin1W;
        for (int hh = 0; hh < 64; ++hh) {
            int h = hbase + hh;
            float4 wv = wb[h*64 + l];
            float a2 = sv.x*wv.x + sv.y*wv.y + sv.z*wv.z + sv.w*wv.w;
            #pragma unroll
            for (int m = 32; m >= 1; m >>= 1) a2 += __shfl_xor(a2, m, 64);
            if (l == 0) {
                a2 += grp ? Bg1[k*128 + h] : lin1b[h];
                a2 = fmaxf(a2, 0.f);
                if (grp) g2[h] = a2; else o2[h] = a2;
            }
        }
    }
    __syncthreads();

    // ---- layer 2: 128 -> 1, no relu ----
    {
        int h = t & 127;
        bool grp = (t >= 128);
        float v = grp ? g2[h] * Wg2[k*128 + h] : o2[h] * lin2W[h];
        red[t] = v;
        __syncthreads();
        for (int s = 64; s >= 1; s >>= 1) {
            if ((t & 127) < s) red[t] += red[t + s];
            __syncthreads();
        }
        if (t == 0) {
            out[(size_t)b*2 + 0] = red[0]   + lin2b[0];
            out[(size_t)b*2 + 1] = red[128] + Bg2[k];
        }
    }
}

extern "C" void kernel_launch(void* const* d_in, const int* in_sizes, int n_in,
                              void* d_out, int out_size, void* d_ws, size_t ws_size,
                              hipStream_t stream) {
    (void)in_sizes; (void)n_in; (void)out_size; (void)ws_size;
    const int* uf0 = (const int*)d_in[0];
    const int* uf1 = (const int*)d_in[1];
    const int* uf2 = (const int*)d_in[2];
    const int* if0 = (const int*)d_in[3];
    const int* if1 = (const int*)d_in[4];
    const int* if2 = (const int*)d_in[5];
    const int* if3 = (const int*)d_in[6];
    const int* sq0 = (const int*)d_in[7];
    const int* sq1 = (const int*)d_in[8];
    const int* sq2 = (const int*)d_in[9];
    const int* sq3 = (const int*)d_in[10];
    const float* ut0 = (const float*)d_in[11];
    const float* ut1 = (const float*)d_in[12];
    const float* ut2 = (const float*)d_in[13];
    const float* it0 = (const float*)d_in[14];
    const float* it1 = (const float*)d_in[15];
    const float* it2 = (const float*)d_in[16];
    const float* it3 = (const float*)d_in[17];
    const float* protos = (const float*)d_in[18];
    const float* wtb0W = (const float*)d_in[19];
    const float* wtb0b = (const float*)d_in[20];
    const float* wtw0W = (const float*)d_in[21];
    const float* wtw0b = (const float*)d_in[22];
    const float* lin0W = (const float*)d_in[23];
    const float* lin0b = (const float*)d_in[24];
    const float* wtb1W = (const float*)d_in[25];
    const float* wtb1b = (const float*)d_in[26];
    const float* wtw1W = (const float*)d_in[27];
    const float* wtw1b = (const float*)d_in[28];
    const float* lin1W = (const float*)d_in[29];
    const float* lin1b = (const float*)d_in[30];
    const float* wtb2W = (const float*)d_in[31];
    const float* wtb2b = (const float*)d_in[32];
    const float* wtw2W = (const float*)d_in[33];
    const float* wtw2b = (const float*)d_in[34];
    const float* lin2W = (const float*)d_in[35];
    const float* lin2b = (const float*)d_in[36];
    float* out = (float*)d_out;

    // workspace carve-up (floats); every chunk is a multiple of 4 floats -> 16B aligned
    float* ws   = (float*)d_ws;
    float* pn_t = ws;                       // 4096
    int*   kidx = (int*)(ws + 4096);        // 512
    int*   order= (int*)(ws + 4096 + 512);  // 512
    float* xbuf = ws + 4096 + 1024;         // 512*960 = 491520
    float* Bg0  = xbuf + 491520;            // 4096
    float* Bg1  = Bg0 + 4096;               // 2048
    float* Bg2  = Bg1 + 2048;               // 16
    float* Wg0  = Bg2 + 16;                 // 3932160
    float* Wg1  = Wg0 + 3932160;            // 524288
    float* Wg2  = Wg1 + 524288;             // 2048
    // total ~19.8 MB

    k_protonorm<<<1, 256, 0, stream>>>(protos, pn_t);
    k_embed<<<NB, 512, 0, stream>>>(uf0, uf1, uf2, if0, if1, if2, if3,
                                    sq0, sq1, sq2, sq3,
                                    ut0, ut1, ut2, it0, it1, it2, it3,
                                    protos, xbuf, kidx);
    k_sort<<<1, 512, 0, stream>>>(kidx, order);
    k_hyper<<<1092, 256, 0, stream>>>(pn_t,
                                      wtw0W, wtw0b, lin0W, Wg0,
                                      wtw1W, wtw1b, lin1W, Wg1,
                                      wtw2W, wtw2b, lin2W, Wg2,
                                      wtb0W, wtb0b, lin0b, Bg0,
                                      wtb1W, wtb1b, lin1b, Bg1,
                                      wtb2W, wtb2b, lin2b, Bg2);
    k_mlp<<<NB, 256, 0, stream>>>(xbuf, kidx, order,
                                  lin0W, lin0b, lin1W, lin1b, lin2W, lin2b,
                                  Wg0, Bg0, Wg1, Bg1, Wg2, Bg2, out);
}